// Round 2
// 213.200 us; speedup vs baseline: 1.0502x; 1.0502x over previous
//
#include <hip/hip_runtime.h>
#include <math.h>

#define NBINS 4096
#define CAP   4096
#define MAXC  300
#define MAXCP 320
#define TOPN  100

// Shared box-decode; expression-identical to previous rounds (absmax was 0.0).
__device__ __forceinline__ void decode4(float x1, float y1, float x2, float y2,
                                        float4 d4, float Wimg, float Himg,
                                        float& bx1, float& by1, float& bx2, float& by2)
{
    float w  = x2 - x1 + 1.0f;
    float h  = y2 - y1 + 1.0f;
    float cx = x1 + 0.5f*(w - 1.0f);
    float cy = y1 + 0.5f*(h - 1.0f);
    float d0 = d4.x*0.1f, d1 = d4.y*0.1f, d2 = d4.z*0.2f, d3 = d4.w*0.2f;
    float pcx = d0*w + cx;
    float pcy = d1*h + cy;
    float pw  = expf(d2)*w;
    float ph  = expf(d3)*h;
    bx1 = fminf(fmaxf(pcx - 0.5f*(pw-1.0f), 0.0f), Wimg-1.0f);
    by1 = fminf(fmaxf(pcy - 0.5f*(ph-1.0f), 0.0f), Himg-1.0f);
    bx2 = fminf(fmaxf(pcx + 0.5f*(pw-1.0f), 0.0f), Wimg-1.0f);
    by2 = fminf(fmaxf(pcy + 0.5f*(ph-1.0f), 0.0f), Himg-1.0f);
}

// ---------------- pass 1: 4 ROIs/thread, float4 loads, scores only (NO atomics) ----------------
__global__ __launch_bounds__(256)
void rcnn_pass1(const float4* __restrict__ cls4, const float4* __restrict__ bbox4,
                const float4* __restrict__ rois4, const float* __restrict__ iminfo,
                float4* __restrict__ scores4,
                unsigned int* __restrict__ hist, unsigned int* __restrict__ counter, int Ng)
{
    // block 0 zero-inits hist + counter (replaces two hipMemsetAsync dispatches);
    // safe: hist/counter are only touched by later kernels (after this one completes).
    if (blockIdx.x == 0) {
        for (int k = threadIdx.x; k < NBINS; k += 256) hist[k] = 0u;
        if (threadIdx.x == 0) *counter = 0u;
    }

    int g = blockIdx.x * blockDim.x + threadIdx.x;
    if (g >= Ng) return;

    float c[20], q[20];
    #pragma unroll
    for (int v = 0; v < 5; v++) {
        float4 cv = cls4[5*g + v];
        c[4*v] = cv.x; c[4*v+1] = cv.y; c[4*v+2] = cv.z; c[4*v+3] = cv.w;
        float4 rv = rois4[5*g + v];
        q[4*v] = rv.x; q[4*v+1] = rv.y; q[4*v+2] = rv.z; q[4*v+3] = rv.w;
    }
    float Himg = iminfo[0], Wimg = iminfo[1];

    float s[4];
    #pragma unroll
    for (int j = 0; j < 4; j++) {
        float p0 = c[5*j], p1 = c[5*j+1], p2 = c[5*j+2], p3 = c[5*j+3], p4 = c[5*j+4];
        float m = p1; int a = 1;
        if (p2 > m) { m = p2; a = 2; }
        if (p3 > m) { m = p3; a = 3; }
        if (p4 > m) { m = p4; a = 4; }
        float sc = -1.0f;
        if (((1.0f - p0) >= 0.2f) && (m > 0.1f)) {
            float4 d4 = bbox4[20*g + 5*j + a];
            float bx1, by1, bx2, by2;
            decode4(q[5*j+1], q[5*j+2], q[5*j+3], q[5*j+4], d4, Wimg, Himg, bx1, by1, bx2, by2);
            float bw = bx2 - bx1 + 1.0f;
            float bh = by2 - by1 + 1.0f;
            if ((bw >= 6.0f) || (bh >= 6.0f)) sc = m;
        }
        s[j] = sc;
    }
    scores4[g] = make_float4(s[0], s[1], s[2], s[3]);
}

// ---------------- pass 1b: LDS histogram over scores (few blocks, coalesced flush) ----------------
__global__ __launch_bounds__(1024)
void rcnn_hist(const float4* __restrict__ scores4, unsigned int* __restrict__ hist, int Ng)
{
    __shared__ unsigned int lh[NBINS];
    const int t = threadIdx.x;
    for (int k = t; k < NBINS; k += 1024) lh[k] = 0u;
    __syncthreads();

    int stride = gridDim.x * 1024;
    for (int g = blockIdx.x * 1024 + t; g < Ng; g += stride) {
        float4 s4 = scores4[g];
        float ss[4] = { s4.x, s4.y, s4.z, s4.w };
        #pragma unroll
        for (int j = 0; j < 4; j++) {
            float s = ss[j];
            if (s > -0.5f) {
                int bin = (int)(s * (float)NBINS);
                bin = bin > NBINS-1 ? NBINS-1 : bin;
                atomicAdd(&lh[bin], 1u);
            }
        }
    }
    __syncthreads();
    for (int k = t; k < NBINS; k += 1024) {
        unsigned int v = lh[k];
        if (v) atomicAdd(&hist[k], v);
    }
}

// ---------------- pass 2: threshold bin tau (largest with suffix >= 300) ----------------
__global__ __launch_bounds__(1024)
void rcnn_pass2(const unsigned int* __restrict__ hist, int* __restrict__ taubin)
{
    __shared__ unsigned int suf[1024];
    __shared__ int g_sh;
    int t = threadIdx.x;
    unsigned int v = hist[4*t] + hist[4*t+1] + hist[4*t+2] + hist[4*t+3];
    suf[t] = v;
    __syncthreads();
    for (int d = 1; d < 1024; d <<= 1) {
        unsigned int add = (t + d < 1024) ? suf[t + d] : 0u;
        __syncthreads();
        suf[t] += add;
        __syncthreads();
    }
    if (t == 0) g_sh = -1;
    __syncthreads();
    if (suf[t] >= MAXC && (t == 1023 || suf[t+1] < MAXC)) g_sh = t;
    __syncthreads();
    if (t == 0) {
        int g = g_sh;
        int tau = 0;
        if (g >= 0) {
            unsigned int cum = (g == 1023) ? 0u : suf[g+1];
            tau = 4*g;
            for (int k = 3; k >= 0; k--) {
                cum += hist[4*g + k];
                if (cum >= MAXC) { tau = 4*g + k; break; }
            }
        }
        *taubin = tau;
    }
}

// ---------------- pass 3: compact candidates above threshold (float4 reads) ----------------
__global__ __launch_bounds__(256)
void rcnn_pass3(const float4* __restrict__ scores4, const int* __restrict__ taubin,
                float* __restrict__ cscore, int* __restrict__ cidx,
                unsigned int* __restrict__ counter, int Ng)
{
    int g = blockIdx.x * blockDim.x + threadIdx.x;
    if (g >= Ng) return;
    float4 s4 = scores4[g];
    int tau = *taubin;
    float ss[4] = { s4.x, s4.y, s4.z, s4.w };
    #pragma unroll
    for (int j = 0; j < 4; j++) {
        float s = ss[j];
        if (s > -0.5f) {
            int bin = (int)(s * (float)NBINS);
            bin = bin > NBINS-1 ? NBINS-1 : bin;
            if (bin >= tau) {
                unsigned int pos = atomicAdd(counter, 1u);
                if (pos < CAP) { cscore[pos] = s; cidx[pos] = 4*g + j; }
            }
        }
    }
}

// ---------------- final: rank sort -> decode -> bitmask NMS (ctz scan, early-stop) -> top-100 ----------------
__global__ __launch_bounds__(1024)
void rcnn_final(const float* __restrict__ cls, const float* __restrict__ bbox,
                const float* __restrict__ rois, const float* __restrict__ iminfo,
                const float* __restrict__ cscore, const int* __restrict__ cidx,
                const unsigned int* __restrict__ counter, float* __restrict__ out)
{
    __shared__ __align__(16) float s_s[CAP];
    __shared__ __align__(16) int   s_id[CAP];
    __shared__ int   tid_[MAXC];
    __shared__ float bx_[MAXCP][4];
    __shared__ float areaA_[MAXCP];
    __shared__ float pr_[MAXC][5];
    __shared__ unsigned long long sup[MAXC][5];
    __shared__ unsigned long long maskw[5];
    __shared__ float orows[TOPN*10];
    __shared__ int   kept_list[TOPN];
    __shared__ int   s_kept;
    const int t  = threadIdx.x;
    const int NT = 1024;
    int M = (int)*counter; if (M > CAP) M = CAP;

    for (int i = t; i < M; i += NT)  { s_s[i] = cscore[i]; s_id[i] = cidx[i]; }
    for (int r = t; r < MAXC; r += NT) tid_[r] = -1;
    for (int r = t; r < MAXCP; r += NT) {
        bx_[r][0]=0.0f; bx_[r][1]=0.0f; bx_[r][2]=0.0f; bx_[r][3]=0.0f; areaA_[r]=0.0f;
    }
    if (t < 5) maskw[t] = 0ull;
    for (int k = t; k < TOPN*10; k += NT) orows[k] = 0.0f;
    __syncthreads();

    // exact stable rank: (score desc, index asc) == jax.lax.top_k order.
    // b128 LDS reads (4 cands/iter) so loads pipeline instead of 1 dependent
    // scalar LDS round-trip per j.
    {
        const float4* sv = (const float4*)s_s;
        const int4*   dv = (const int4*)s_id;
        int M4 = M >> 2;
        for (int i = t; i < M; i += NT) {
            float si = s_s[i]; int di = s_id[i];
            int r = 0;
            for (int jj = 0; jj < M4; jj++) {
                float4 sj = sv[jj]; int4 dj = dv[jj];
                r += (sj.x > si) || (sj.x == si && dj.x < di);
                r += (sj.y > si) || (sj.y == si && dj.y < di);
                r += (sj.z > si) || (sj.z == si && dj.z < di);
                r += (sj.w > si) || (sj.w == si && dj.w < di);
            }
            for (int j = M4 << 2; j < M; j++) {
                float sj = s_s[j]; int dj = s_id[j];
                r += (sj > si) || (sj == si && dj < di);
            }
            if (r < MAXC) tid_[r] = di;
        }
    }
    __syncthreads();

    // decode boxes + gather probs for the ranked 300; precompute areas; validity mask
    float Himg = iminfo[0], Wimg = iminfo[1];
    for (int r = t; r < MAXC; r += NT) {
        int i = tid_[r];
        if (i >= 0) {
            float p0 = cls[5*i], p1 = cls[5*i+1], p2 = cls[5*i+2], p3 = cls[5*i+3], p4 = cls[5*i+4];
            pr_[r][0]=p0; pr_[r][1]=p1; pr_[r][2]=p2; pr_[r][3]=p3; pr_[r][4]=p4;
            float m = p1; int a = 1;
            if (p2 > m) { m = p2; a = 2; }
            if (p3 > m) { m = p3; a = 3; }
            if (p4 > m) { m = p4; a = 4; }
            float4 d4 = ((const float4*)bbox)[5*i + a];
            float bx1, by1, bx2, by2;
            decode4(rois[5*i+1], rois[5*i+2], rois[5*i+3], rois[5*i+4], d4, Wimg, Himg, bx1, by1, bx2, by2);
            bx_[r][0]=bx1; bx_[r][1]=by1; bx_[r][2]=bx2; bx_[r][3]=by2;
            areaA_[r] = (bx2-bx1)*(by2-by1);
            atomicOr(&maskw[r>>6], 1ull << (r & 63));
        }
    }
    __syncthreads();

    // parallel suppression bitmask matrix: sup[i][w] bit b = (j=64w+b suppressible by i)
    // IEEE division kept on purpose: bit-exact keep-mask vs the JAX reference.
    for (int task = t; task < MAXC*5; task += NT) {
        int w = task / MAXC;
        int i = task - w*MAXC;
        unsigned long long bits = 0ull;
        int j0 = w << 6;
        if (j0 + 63 > i) {
            float ax1 = bx_[i][0], ay1 = bx_[i][1], ax2 = bx_[i][2], ay2 = bx_[i][3];
            float areaA = areaA_[i];
            for (int b = 0; b < 64; b++) {
                int j = j0 + b;
                float lx = fmaxf(ax1, bx_[j][0]), ly = fmaxf(ay1, bx_[j][1]);
                float rx = fminf(ax2, bx_[j][2]), ry = fminf(ay2, bx_[j][3]);
                float iw = fmaxf(rx - lx, 0.0f), ih = fmaxf(ry - ly, 0.0f);
                float inter = iw * ih;
                float iou = inter / (areaA + areaA_[j] - inter);  // NaN/neg-safe: compare false
                bits |= (iou > 0.5f) ? (1ull << b) : 0ull;
            }
            unsigned long long jgt = (i < j0) ? ~0ull
                                  : ((i - j0) >= 63 ? 0ull : ~((1ull << (i - j0 + 1)) - 1ull));
            bits &= jgt & maskw[w];
        }
        sup[i][w] = bits;
    }
    __syncthreads();

    // serial greedy scan, but: (a) ctz jumps straight to the next alive bit,
    // (b) EXACT early stop at the 100th kept box — suppression only flows to
    // j>i and the output only reads the first TOPN kept, so bits after the
    // 100th kept are irrelevant. ~300 -> ~105 dependent-LDS iterations.
    if (t == 0) {
        unsigned long long k0=maskw[0], k1=maskw[1], k2=maskw[2], k3=maskw[3], k4=maskw[4];
        int kept = 0;
        #define SCAN_WORD(W, KW)                                                   \
        if (kept < TOPN) {                                                         \
            unsigned long long donem = 0ull;                                       \
            for (;;) {                                                             \
                unsigned long long rem = (KW) & ~donem;                            \
                if (!rem) break;                                                   \
                int b = __builtin_ctzll(rem);                                      \
                int i = (W << 6) + b;                                              \
                kept_list[kept++] = i;                                             \
                if (kept >= TOPN) break;                                           \
                unsigned long long s0 = sup[i][0], s1 = sup[i][1], s2 = sup[i][2], \
                                   s3 = sup[i][3], s4 = sup[i][4];                 \
                k0 &= ~s0; k1 &= ~s1; k2 &= ~s2; k3 &= ~s3; k4 &= ~s4;             \
                donem = (b == 63) ? ~0ull : ((2ull << b) - 1ull);                  \
            }                                                                      \
        }
        SCAN_WORD(0, k0)
        SCAN_WORD(1, k1)
        SCAN_WORD(2, k2)
        SCAN_WORD(3, k3)
        SCAN_WORD(4, k4)
        #undef SCAN_WORD
        s_kept = kept;
    }
    __syncthreads();

    // direct output from kept_list (popcount-prefix pass eliminated)
    int kept = s_kept;
    if (t < kept) {
        int r = kept_list[t];
        float* row = &orows[t*10];
        row[0] = 0.0f;
        row[1] = bx_[r][0]; row[2] = bx_[r][1]; row[3] = bx_[r][2]; row[4] = bx_[r][3];
        row[5] = pr_[r][0]; row[6] = pr_[r][1]; row[7] = pr_[r][2]; row[8] = pr_[r][3]; row[9] = pr_[r][4];
    }
    __syncthreads();
    for (int k = t; k < TOPN*10; k += NT) out[k] = orows[k];
}

extern "C" void kernel_launch(void* const* d_in, const int* in_sizes, int n_in,
                              void* d_out, int out_size, void* d_ws, size_t ws_size,
                              hipStream_t stream)
{
    const float* cls    = (const float*)d_in[0];
    const float* bbox   = (const float*)d_in[1];
    const float* rois   = (const float*)d_in[2];
    const float* iminfo = (const float*)d_in[3];
    int N  = in_sizes[0] / 5;
    int Ng = N / 4;  // N = 1e6, divisible by 4

    char* ws = (char*)d_ws;
    float* scores = (float*)ws;
    size_t off = ((size_t)N * 4 + 255) & ~(size_t)255;
    unsigned int* hist    = (unsigned int*)(ws + off); off += NBINS * 4;
    int*          taubin  = (int*)(ws + off);          off += 256;
    unsigned int* counter = (unsigned int*)(ws + off); off += 256;
    float*        cscore  = (float*)(ws + off);        off += CAP * 4;
    int*          cidx    = (int*)(ws + off);          off += CAP * 4;

    int blocksG = (Ng + 255) / 256;
    rcnn_pass1<<<blocksG, 256, 0, stream>>>((const float4*)cls, (const float4*)bbox,
                                            (const float4*)rois, iminfo,
                                            (float4*)scores, hist, counter, Ng);
    rcnn_hist<<<64, 1024, 0, stream>>>((const float4*)scores, hist, Ng);
    rcnn_pass2<<<1, 1024, 0, stream>>>(hist, taubin);
    rcnn_pass3<<<blocksG, 256, 0, stream>>>((const float4*)scores, taubin,
                                            cscore, cidx, counter, Ng);
    rcnn_final<<<1, 1024, 0, stream>>>(cls, bbox, rois, iminfo,
                                       cscore, cidx, counter, (float*)d_out);
}

// Round 4
// 206.462 us; speedup vs baseline: 1.0845x; 1.0326x over previous
//
#include <hip/hip_runtime.h>
#include <math.h>

#define NBINS 4096
#define CAP   4096
#define MAXC  300
#define MAXCP 320
#define NTASK (MAXC*5)
#define TOPN  100

// Shared box-decode; expression-identical to previous rounds (absmax was 0.0).
__device__ __forceinline__ void decode4(float x1, float y1, float x2, float y2,
                                        float4 d4, float Wimg, float Himg,
                                        float& bx1, float& by1, float& bx2, float& by2)
{
    float w  = x2 - x1 + 1.0f;
    float h  = y2 - y1 + 1.0f;
    float cx = x1 + 0.5f*(w - 1.0f);
    float cy = y1 + 0.5f*(h - 1.0f);
    float d0 = d4.x*0.1f, d1 = d4.y*0.1f, d2 = d4.z*0.2f, d3 = d4.w*0.2f;
    float pcx = d0*w + cx;
    float pcy = d1*h + cy;
    float pw  = expf(d2)*w;
    float ph  = expf(d3)*h;
    bx1 = fminf(fmaxf(pcx - 0.5f*(pw-1.0f), 0.0f), Wimg-1.0f);
    by1 = fminf(fmaxf(pcy - 0.5f*(ph-1.0f), 0.0f), Himg-1.0f);
    bx2 = fminf(fmaxf(pcx + 0.5f*(pw-1.0f), 0.0f), Wimg-1.0f);
    by2 = fminf(fmaxf(pcy + 0.5f*(ph-1.0f), 0.0f), Himg-1.0f);
}

// ---------------- pass 1: 4 ROIs/thread, float4 loads, scores only (NO atomics) ----------------
__global__ __launch_bounds__(256)
void rcnn_pass1(const float4* __restrict__ cls4, const float4* __restrict__ bbox4,
                const float4* __restrict__ rois4, const float* __restrict__ iminfo,
                float4* __restrict__ scores4,
                unsigned int* __restrict__ hist, unsigned int* __restrict__ counter, int Ng)
{
    if (blockIdx.x == 0) {
        for (int k = threadIdx.x; k < NBINS; k += 256) hist[k] = 0u;
        if (threadIdx.x == 0) *counter = 0u;
    }

    int g = blockIdx.x * blockDim.x + threadIdx.x;
    if (g >= Ng) return;

    float c[20], q[20];
    #pragma unroll
    for (int v = 0; v < 5; v++) {
        float4 cv = cls4[5*g + v];
        c[4*v] = cv.x; c[4*v+1] = cv.y; c[4*v+2] = cv.z; c[4*v+3] = cv.w;
        float4 rv = rois4[5*g + v];
        q[4*v] = rv.x; q[4*v+1] = rv.y; q[4*v+2] = rv.z; q[4*v+3] = rv.w;
    }
    float Himg = iminfo[0], Wimg = iminfo[1];

    float s[4];
    #pragma unroll
    for (int j = 0; j < 4; j++) {
        float p0 = c[5*j], p1 = c[5*j+1], p2 = c[5*j+2], p3 = c[5*j+3], p4 = c[5*j+4];
        float m = p1; int a = 1;
        if (p2 > m) { m = p2; a = 2; }
        if (p3 > m) { m = p3; a = 3; }
        if (p4 > m) { m = p4; a = 4; }
        float sc = -1.0f;
        if (((1.0f - p0) >= 0.2f) && (m > 0.1f)) {
            float4 d4 = bbox4[20*g + 5*j + a];
            float bx1, by1, bx2, by2;
            decode4(q[5*j+1], q[5*j+2], q[5*j+3], q[5*j+4], d4, Wimg, Himg, bx1, by1, bx2, by2);
            float bw = bx2 - bx1 + 1.0f;
            float bh = by2 - by1 + 1.0f;
            if ((bw >= 6.0f) || (bh >= 6.0f)) sc = m;
        }
        s[j] = sc;
    }
    scores4[g] = make_float4(s[0], s[1], s[2], s[3]);
}

// ---------------- pass 1b: LDS histogram over scores (few blocks, coalesced flush) ----------------
__global__ __launch_bounds__(1024)
void rcnn_hist(const float4* __restrict__ scores4, unsigned int* __restrict__ hist, int Ng)
{
    __shared__ unsigned int lh[NBINS];
    const int t = threadIdx.x;
    for (int k = t; k < NBINS; k += 1024) lh[k] = 0u;
    __syncthreads();

    int stride = gridDim.x * 1024;
    for (int g = blockIdx.x * 1024 + t; g < Ng; g += stride) {
        float4 s4 = scores4[g];
        float ss[4] = { s4.x, s4.y, s4.z, s4.w };
        #pragma unroll
        for (int j = 0; j < 4; j++) {
            float s = ss[j];
            if (s > -0.5f) {
                int bin = (int)(s * (float)NBINS);
                bin = bin > NBINS-1 ? NBINS-1 : bin;
                atomicAdd(&lh[bin], 1u);
            }
        }
    }
    __syncthreads();
    for (int k = t; k < NBINS; k += 1024) {
        unsigned int v = lh[k];
        if (v) atomicAdd(&hist[k], v);
    }
}

// ---------------- pass 2: threshold bin tau — single-wave register suffix scan ----------------
// tau = largest bin b with suffix_count(b) >= MAXC, else 0 (bit-identical to old 1024-thread version).
__global__ __launch_bounds__(64)
void rcnn_pass2(const unsigned int* __restrict__ hist, int* __restrict__ taubin)
{
    const int t = threadIdx.x;   // one wave
    const uint4* h4 = (const uint4*)hist;
    uint4 v[16];
    #pragma unroll
    for (int j = 0; j < 16; j++) v[j] = h4[t*16 + j];   // lane t owns bins [64t, 64t+64)
    unsigned int chunk = 0;
    #pragma unroll
    for (int j = 0; j < 16; j++) chunk += v[j].x + v[j].y + v[j].z + v[j].w;

    // inclusive suffix-sum across 64 lanes
    unsigned int sfx = chunk;
    #pragma unroll
    for (int d = 1; d < 64; d <<= 1) {
        unsigned int o = __shfl_down(sfx, d, 64);
        if (t + d < 64) sfx += o;
    }
    unsigned int nxt = sfx - chunk;              // suffix of bins >= 64(t+1)
    bool found = (sfx >= MAXC) && (nxt < MAXC);  // unique boundary lane (suffix monotone)
    unsigned long long bal = __ballot(found);
    if (found) {
        unsigned int cum = nxt;
        int tau = 64*t;
        #pragma unroll
        for (int k = 15; k >= 0; k--) {
            cum += v[k].w; if (cum >= MAXC) { tau = 64*t + 4*k + 3; goto done; }
            cum += v[k].z; if (cum >= MAXC) { tau = 64*t + 4*k + 2; goto done; }
            cum += v[k].y; if (cum >= MAXC) { tau = 64*t + 4*k + 1; goto done; }
            cum += v[k].x; if (cum >= MAXC) { tau = 64*t + 4*k + 0; goto done; }
        }
        done:
        *taubin = tau;
    }
    if (bal == 0ull && t == 0) *taubin = 0;
}

// ---------------- pass 3: compact candidates above threshold (float4 reads) ----------------
__global__ __launch_bounds__(256)
void rcnn_pass3(const float4* __restrict__ scores4, const int* __restrict__ taubin,
                float* __restrict__ cscore, int* __restrict__ cidx,
                unsigned int* __restrict__ counter, int Ng)
{
    int g = blockIdx.x * blockDim.x + threadIdx.x;
    if (g >= Ng) return;
    float4 s4 = scores4[g];
    int tau = *taubin;
    float ss[4] = { s4.x, s4.y, s4.z, s4.w };
    #pragma unroll
    for (int j = 0; j < 4; j++) {
        float s = ss[j];
        if (s > -0.5f) {
            int bin = (int)(s * (float)NBINS);
            bin = bin > NBINS-1 ? NBINS-1 : bin;
            if (bin >= tau) {
                unsigned int pos = atomicAdd(counter, 1u);
                if (pos < CAP) { cscore[pos] = s; cidx[pos] = 4*g + j; }
            }
        }
    }
}

// ---------------- rank: exact stable top-300 rank + decode (1 block) ----------------
__global__ __launch_bounds__(1024)
void rcnn_rank(const float* __restrict__ cls, const float* __restrict__ bbox,
               const float* __restrict__ rois, const float* __restrict__ iminfo,
               const float* __restrict__ cscore, const int* __restrict__ cidx,
               const unsigned int* __restrict__ counter,
               float4* __restrict__ bxg, float* __restrict__ areag,
               float* __restrict__ prg, unsigned long long* __restrict__ maskg)
{
    __shared__ __align__(16) float s_s[CAP];
    __shared__ __align__(16) int   s_id[CAP];
    __shared__ int tid_[MAXC];
    __shared__ unsigned long long maskw[5];
    const int t  = threadIdx.x;
    const int NT = 1024;
    int M = (int)*counter; if (M > CAP) M = CAP;

    for (int i = t; i < M; i += NT)  { s_s[i] = cscore[i]; s_id[i] = cidx[i]; }
    for (int r = t; r < MAXC; r += NT) tid_[r] = -1;
    if (t < 5) maskw[t] = 0ull;
    __syncthreads();

    // exact stable rank: (score desc, index asc) == jax.lax.top_k order; b128 LDS reads
    {
        const float4* sv = (const float4*)s_s;
        const int4*   dv = (const int4*)s_id;
        int M4 = M >> 2;
        for (int i = t; i < M; i += NT) {
            float si = s_s[i]; int di = s_id[i];
            int r = 0;
            for (int jj = 0; jj < M4; jj++) {
                float4 sj = sv[jj]; int4 dj = dv[jj];
                r += (sj.x > si) || (sj.x == si && dj.x < di);
                r += (sj.y > si) || (sj.y == si && dj.y < di);
                r += (sj.z > si) || (sj.z == si && dj.z < di);
                r += (sj.w > si) || (sj.w == si && dj.w < di);
            }
            for (int j = M4 << 2; j < M; j++) {
                float sj = s_s[j]; int dj = s_id[j];
                r += (sj > si) || (sj == si && dj < di);
            }
            if (r < MAXC) tid_[r] = di;
        }
    }
    __syncthreads();

    // decode boxes + gather probs for the ranked 300; precompute areas; validity mask
    float Himg = iminfo[0], Wimg = iminfo[1];
    for (int r = t; r < MAXCP; r += NT) {
        int i = (r < MAXC) ? tid_[r] : -1;
        float4 bx = make_float4(0.0f, 0.0f, 0.0f, 0.0f);
        float ar = 0.0f;
        if (i >= 0) {
            float p0 = cls[5*i], p1 = cls[5*i+1], p2 = cls[5*i+2], p3 = cls[5*i+3], p4 = cls[5*i+4];
            prg[5*r+0]=p0; prg[5*r+1]=p1; prg[5*r+2]=p2; prg[5*r+3]=p3; prg[5*r+4]=p4;
            float m = p1; int a = 1;
            if (p2 > m) { m = p2; a = 2; }
            if (p3 > m) { m = p3; a = 3; }
            if (p4 > m) { m = p4; a = 4; }
            float4 d4 = ((const float4*)bbox)[5*i + a];
            float bx1, by1, bx2, by2;
            decode4(rois[5*i+1], rois[5*i+2], rois[5*i+3], rois[5*i+4], d4, Wimg, Himg, bx1, by1, bx2, by2);
            bx = make_float4(bx1, by1, bx2, by2);
            ar = (bx2-bx1)*(by2-by1);
            atomicOr(&maskw[r>>6], 1ull << (r & 63));
        }
        bxg[r] = bx; areag[r] = ar;
    }
    __syncthreads();
    if (t < 5) maskg[t] = maskw[t];
}

// ---------------- sup: suppression bitmask matrix, parallel across CUs (1 wave/block) ----------------
__global__ __launch_bounds__(64)
void rcnn_sup(const float4* __restrict__ bxg, const float* __restrict__ areag,
              const unsigned long long* __restrict__ maskg,
              unsigned long long* __restrict__ supg)
{
    __shared__ float4 bxs[MAXCP];
    __shared__ float  ars[MAXCP];
    const int t = threadIdx.x;
    for (int r = t; r < MAXCP; r += 64) { bxs[r] = bxg[r]; ars[r] = areag[r]; }
    __syncthreads();

    int task = blockIdx.x * 64 + t;
    if (task >= NTASK) return;
    int w = task / MAXC;
    int i = task - w * MAXC;
    unsigned long long bits = 0ull;
    int j0 = w << 6;
    if (j0 + 63 > i) {
        float4 bi = bxs[i];
        float areaA = ars[i];
        // IEEE division kept on purpose: bit-exact keep-mask vs the JAX reference.
        for (int b = 0; b < 64; b++) {
            int j = j0 + b;
            float4 bj = bxs[j];
            float lx = fmaxf(bi.x, bj.x), ly = fmaxf(bi.y, bj.y);
            float rx = fminf(bi.z, bj.z), ry = fminf(bi.w, bj.w);
            float iw = fmaxf(rx - lx, 0.0f), ih = fmaxf(ry - ly, 0.0f);
            float inter = iw * ih;
            float iou = inter / (areaA + ars[j] - inter);  // NaN/neg-safe: compare false
            bits |= (iou > 0.5f) ? (1ull << b) : 0ull;
        }
        unsigned long long jgt = (i < j0) ? ~0ull
                              : ((i - j0) >= 63 ? 0ull : ~((1ull << (i - j0 + 1)) - 1ull));
        bits &= jgt & maskg[w];
    }
    supg[i*6 + w] = bits;   // row stride 6 (48B) for aligned b128 loads in scan
}

// ---------------- scan: serial greedy NMS (ctz, early-stop) + output (1 block) ----------------
__global__ __launch_bounds__(1024)
void rcnn_scan(const float4* __restrict__ bxg, const float* __restrict__ prg,
               const unsigned long long* __restrict__ maskg,
               const unsigned long long* __restrict__ supg, float* __restrict__ out)
{
    __shared__ __align__(16) unsigned long long sup[MAXC*6];
    __shared__ unsigned long long maskw[5];
    __shared__ float orows[TOPN*10];
    __shared__ int   kept_list[TOPN];
    __shared__ int   s_kept;
    const int t  = threadIdx.x;
    const int NT = 1024;

    // cooperative sup -> LDS (900 x b128)
    {
        const ulonglong2* sg2 = (const ulonglong2*)supg;
        ulonglong2* sl2 = (ulonglong2*)sup;
        for (int k = t; k < (MAXC*6)/2; k += NT) sl2[k] = sg2[k];
    }
    if (t < 5) maskw[t] = maskg[t];
    for (int k = t; k < TOPN*10; k += NT) orows[k] = 0.0f;
    __syncthreads();

    // serial greedy scan: ctz jumps to next alive bit; EXACT early stop at 100th kept
    // (suppression only flows to j>i; output reads only the first TOPN kept).
    if (t == 0) {
        unsigned long long k0=maskw[0], k1=maskw[1], k2=maskw[2], k3=maskw[3], k4=maskw[4];
        int kept = 0;
        #define SCAN_WORD(W, KW)                                                   \
        if (kept < TOPN) {                                                         \
            unsigned long long donem = 0ull;                                       \
            for (;;) {                                                             \
                unsigned long long rem = (KW) & ~donem;                            \
                if (!rem) break;                                                   \
                int b = __builtin_ctzll(rem);                                      \
                int i = (W << 6) + b;                                              \
                kept_list[kept++] = i;                                             \
                if (kept >= TOPN) break;                                           \
                unsigned long long s0 = sup[i*6+0], s1 = sup[i*6+1],               \
                                   s2 = sup[i*6+2], s3 = sup[i*6+3],               \
                                   s4 = sup[i*6+4];                                \
                k0 &= ~s0; k1 &= ~s1; k2 &= ~s2; k3 &= ~s3; k4 &= ~s4;             \
                donem = (b == 63) ? ~0ull : ((2ull << b) - 1ull);                  \
            }                                                                      \
        }
        SCAN_WORD(0, k0)
        SCAN_WORD(1, k1)
        SCAN_WORD(2, k2)
        SCAN_WORD(3, k3)
        SCAN_WORD(4, k4)
        #undef SCAN_WORD
        s_kept = kept;
    }
    __syncthreads();

    int kept = s_kept;
    if (t < kept) {
        int r = kept_list[t];
        float4 bx = bxg[r];
        float* row = &orows[t*10];
        row[0] = 0.0f;
        row[1] = bx.x; row[2] = bx.y; row[3] = bx.z; row[4] = bx.w;
        row[5] = prg[5*r+0]; row[6] = prg[5*r+1]; row[7] = prg[5*r+2];
        row[8] = prg[5*r+3]; row[9] = prg[5*r+4];
    }
    __syncthreads();
    for (int k = t; k < TOPN*10; k += NT) out[k] = orows[k];
}

extern "C" void kernel_launch(void* const* d_in, const int* in_sizes, int n_in,
                              void* d_out, int out_size, void* d_ws, size_t ws_size,
                              hipStream_t stream)
{
    const float* cls    = (const float*)d_in[0];
    const float* bbox   = (const float*)d_in[1];
    const float* rois   = (const float*)d_in[2];
    const float* iminfo = (const float*)d_in[3];
    int N  = in_sizes[0] / 5;
    int Ng = N / 4;  // N = 1e6, divisible by 4

    char* ws = (char*)d_ws;
    float* scores = (float*)ws;
    size_t off = ((size_t)N * 4 + 255) & ~(size_t)255;
    unsigned int* hist    = (unsigned int*)(ws + off); off += NBINS * 4;
    int*          taubin  = (int*)(ws + off);          off += 256;
    unsigned int* counter = (unsigned int*)(ws + off); off += 256;
    float*        cscore  = (float*)(ws + off);        off += CAP * 4;
    int*          cidx    = (int*)(ws + off);          off += CAP * 4;
    float4*       bxg     = (float4*)(ws + off);       off += MAXCP * 16;
    float*        areag   = (float*)(ws + off);        off += ((MAXCP * 4 + 255) & ~(size_t)255);
    float*        prg     = (float*)(ws + off);        off += ((MAXC * 5 * 4 + 255) & ~(size_t)255);
    unsigned long long* maskg = (unsigned long long*)(ws + off); off += 256;
    unsigned long long* supg  = (unsigned long long*)(ws + off); off += MAXC * 6 * 8;

    int blocksG = (Ng + 255) / 256;
    rcnn_pass1<<<blocksG, 256, 0, stream>>>((const float4*)cls, (const float4*)bbox,
                                            (const float4*)rois, iminfo,
                                            (float4*)scores, hist, counter, Ng);
    rcnn_hist<<<64, 1024, 0, stream>>>((const float4*)scores, hist, Ng);
    rcnn_pass2<<<1, 64, 0, stream>>>(hist, taubin);
    rcnn_pass3<<<blocksG, 256, 0, stream>>>((const float4*)scores, taubin,
                                            cscore, cidx, counter, Ng);
    rcnn_rank<<<1, 1024, 0, stream>>>(cls, bbox, rois, iminfo,
                                      cscore, cidx, counter,
                                      bxg, areag, prg, maskg);
    rcnn_sup<<<(NTASK + 63) / 64, 64, 0, stream>>>(bxg, areag, maskg, supg);
    rcnn_scan<<<1, 1024, 0, stream>>>(bxg, prg, maskg, supg, (float*)d_out);
}